// Round 1
// baseline (808.511 us; speedup 1.0000x reference)
//
#include <hip/hip_runtime.h>
#include <cstdint>

// ---------------------------------------------------------------------------
// HopeAttention restructured:
//   M_t = a_t M_{t-1} + b_t err_t k_t^T  (gate+clip folded into a,b)
//   err_t = M_{t-1} (cmean_t - kmean_t)  (v_mean = M cmean since out linear in chunk)
//   => M_t = pi_t ( M0 + sum_j phi_j e~_j k_j^T ),  phi_j = B_j/A_j
//      e~_t = M0 dvec_t + sum_{j<t} phi_j (k_j . dvec_t) e~_j   (cheap recurrence)
//   out_t = pi_t ( chunk_t @ M0^T + sum_{j<t} phi_j (chunk_t . k_j) e~_j^T )
//   ||M||_F^2 tracked analytically -> no per-step full-matrix passes.
// Heavy work = bf16 MFMA GEMMs (fp32 accum); only a tiny 16-WG chain kernel is
// sequential.
// ---------------------------------------------------------------------------

typedef __bf16 bf16_t;
typedef __bf16 bf16x8 __attribute__((ext_vector_type(8)));
typedef float f32x4 __attribute__((ext_vector_type(4)));

#define NB 16
#define SEQ 4096
#define DIM 512
#define CHK 64
#define NC 64
#define ROWS (NB * SEQ)   // 65536
#define VHAT_ELEMS ((long)ROWS * DIM)  // 33554432

enum { MODE_F32 = 0, MODE_BF16 = 1, MODE_SILU = 2, MODE_RESID = 3, MODE_MASKPHI = 4, MODE_PI = 5 };

static __device__ __forceinline__ float sigmoidf_(float z) { return 1.f / (1.f + __expf(-z)); }

// ---------------------------------------------------------------------------
// K0: convert weights to bf16 + ||M0||^2 reduction
// ---------------------------------------------------------------------------
__global__ __launch_bounds__(256) void k0_convert(
    const float* __restrict__ M0, const float* __restrict__ W1, const float* __restrict__ W2,
    bf16_t* __restrict__ M0h, bf16_t* __restrict__ W1h, bf16_t* __restrict__ W2h,
    float* __restrict__ n2slot)
{
    int idx = blockIdx.x * 256 + threadIdx.x;
    const int NW = DIM * DIM;
    if (idx < NW) {
        float v = M0[idx];
        M0h[idx] = (bf16_t)v;
        float s = v * v;
        for (int o = 32; o; o >>= 1) s += __shfl_down(s, o);
        if ((threadIdx.x & 63) == 0) atomicAdd(n2slot, s);
    } else if (idx < 2 * NW) {
        int i = idx - NW;
        W1h[i] = (bf16_t)W1[i];
    } else {
        int i = idx - 2 * NW;
        W2h[i] = (bf16_t)W2[i];
    }
}

// ---------------------------------------------------------------------------
// K1: per (b,tc): row norms, k_mean, cmean, dvec, gate scalars; also x -> bf16
// ---------------------------------------------------------------------------
__global__ __launch_bounds__(256) void k1_stats(
    const float* __restrict__ x,
    const float* __restrict__ gate_w, const float* __restrict__ gate_b,
    const float* __restrict__ eta_raw, const float* __restrict__ alpha_raw,
    bf16_t* __restrict__ xh,
    float* __restrict__ kf, bf16_t* __restrict__ kh,
    float* __restrict__ dvf, bf16_t* __restrict__ dvh,
    float* __restrict__ Aarr, float* __restrict__ Barr,
    float* __restrict__ phiarr, float* __restrict__ kkarr)
{
    int tc = blockIdx.x, b = blockIdx.y;
    int tid = threadIdx.x, lane = tid & 63, w = tid >> 6;
    __shared__ float invn[CHK];
    __shared__ float redg[4], redk[4];
    long base = ((long)b * SEQ + (long)tc * CHK) * DIM;

    // pass 1: row norms (wave per 16 rows) + bf16 copy of x
    for (int c = w * 16; c < w * 16 + 16; ++c) {
        const float* row = x + base + (long)c * DIM;
        float4 v0 = ((const float4*)row)[lane * 2];
        float4 v1 = ((const float4*)row)[lane * 2 + 1];
        bf16x8 hv;
        hv[0] = (bf16_t)v0.x; hv[1] = (bf16_t)v0.y; hv[2] = (bf16_t)v0.z; hv[3] = (bf16_t)v0.w;
        hv[4] = (bf16_t)v1.x; hv[5] = (bf16_t)v1.y; hv[6] = (bf16_t)v1.z; hv[7] = (bf16_t)v1.w;
        *(bf16x8*)(xh + base + (long)c * DIM + lane * 8) = hv;
        float s = v0.x*v0.x + v0.y*v0.y + v0.z*v0.z + v0.w*v0.w
                + v1.x*v1.x + v1.y*v1.y + v1.z*v1.z + v1.w*v1.w;
        for (int o = 32; o; o >>= 1) s += __shfl_down(s, o);
        if (lane == 0) {
            float nm = sqrtf(s);
            invn[c] = 1.f / fmaxf(nm, 1e-5f);
        }
    }
    __syncthreads();

    // pass 2: k_mean / cmean over dims
    float pg = 0.f, pkk = 0.f;
    for (int half = 0; half < 2; ++half) {
        int i = half * 256 + tid;
        float s0 = 0.f, s1 = 0.f;
        for (int c = 0; c < CHK; ++c) {
            float v = x[base + (long)c * DIM + i];
            s0 += v;
            s1 += v * invn[c];
        }
        float kv = s1 * (1.f / 64.f);
        float cm = s0 * (1.f / 64.f);
        float dv = cm - kv;
        long o = ((long)b * NC + tc) * DIM + i;
        kf[o] = kv; kh[o] = (bf16_t)kv;
        dvf[o] = dv; dvh[o] = (bf16_t)dv;
        pg += kv * gate_w[i];
        pkk += kv * kv;
    }
    for (int o = 32; o; o >>= 1) { pg += __shfl_down(pg, o); pkk += __shfl_down(pkk, o); }
    if (lane == 0) { redg[w] = pg; redk[w] = pkk; }
    __syncthreads();
    if (tid == 0) {
        float gdot = redg[0] + redg[1] + redg[2] + redg[3] + gate_b[0];
        float kk = redk[0] + redk[1] + redk[2] + redk[3];
        float g = sigmoidf_(gdot);
        float eta = 0.2f * sigmoidf_(eta_raw[0]);
        float alpha = 0.5f + 0.5f * sigmoidf_(alpha_raw[0]);
        float Av = g * alpha + 1.f - g;
        float Bv = g * eta;
        int idx = b * NC + tc;
        Aarr[idx] = Av; Barr[idx] = Bv; phiarr[idx] = Bv / Av; kkarr[idx] = kk;
    }
}

// ---------------------------------------------------------------------------
// K3: Gram matrices KD[b][t][j] = k_j . dvec_t,  KK[b][t][j] = k_j . k_t
// ---------------------------------------------------------------------------
__global__ __launch_bounds__(256) void k3_gram(
    const float* __restrict__ kf, const float* __restrict__ dvf,
    float* __restrict__ KD, float* __restrict__ KK)
{
    int t = blockIdx.x, b = blockIdx.y;
    int tid = threadIdx.x, lane = tid & 63, w = tid >> 6;
    __shared__ float dvt[DIM], ktv[DIM];
    for (int i = tid; i < DIM; i += 256) {
        long o = ((long)b * NC + t) * DIM + i;
        dvt[i] = dvf[o];
        ktv[i] = kf[o];
    }
    __syncthreads();
    for (int j = w * 16; j < w * 16 + 16; ++j) {
        const float* kj = kf + ((long)b * NC + j) * DIM;
        float s1 = 0.f, s2 = 0.f;
        #pragma unroll
        for (int u = 0; u < 8; ++u) {
            float v = kj[lane * 8 + u];
            s1 += v * dvt[lane * 8 + u];
            s2 += v * ktv[lane * 8 + u];
        }
        for (int o = 32; o; o >>= 1) { s1 += __shfl_down(s1, o); s2 += __shfl_down(s2, o); }
        if (lane == 0) {
            KD[((long)b * NC + t) * NC + j] = s1;
            KK[((long)b * NC + t) * NC + j] = s2;
        }
    }
}

// ---------------------------------------------------------------------------
// K4: sequential scalar/vector chain. 1 WG per batch, 512 threads (dim i).
//   e~_t = err0_t + sum_{j<t} phi_j KD[t][j] e~_j      (per-thread reg array)
//   Mk~_t = Mk0_t + sum_{j<t} phi_j KK[t][j] e~_j
//   fro^2 = A^2 n2 + 2AB pi^2 (e~.Mk~) + B^2 pi^2 (e~.e~) kk
// ---------------------------------------------------------------------------
__global__ __launch_bounds__(512) void k4_chain(
    const float* __restrict__ err0,   // [2048][512]: rows 0..1023 = M0 dvec, 1024.. = M0 k
    const float* __restrict__ KD, const float* __restrict__ KK,
    const float* __restrict__ Aarr, const float* __restrict__ Barr,
    const float* __restrict__ phiarr, const float* __restrict__ kkarr,
    const float* __restrict__ n2slot,
    float* __restrict__ Eg, bf16_t* __restrict__ Eth, float* __restrict__ pi_arr)
{
    int b = blockIdx.x;
    int tid = threadIdx.x, lane = tid & 63, w = tid >> 6;
    __shared__ float cA[NC], cB[NC], red[8][2];
    float e[NC];
    #pragma unroll
    for (int j = 0; j < NC; ++j) e[j] = 0.f;   // avoid NaN garbage in predicated MACs

    float pi = 1.f;
    float n2 = n2slot[0];
    for (int t = 0; t < NC; ++t) {
        __syncthreads();
        if (tid < NC) {
            float ph = phiarr[b * NC + tid];
            cA[tid] = ph * KD[((long)b * NC + t) * NC + tid];
            cB[tid] = ph * KK[((long)b * NC + t) * NC + tid];
        }
        __syncthreads();
        float ev = err0[((long)(b * NC + t)) * DIM + tid];
        float mk = err0[((long)(1024 + b * NC + t)) * DIM + tid];
        #pragma unroll
        for (int j = 0; j < NC; ++j) {
            bool pd = j < t;
            float ca = pd ? cA[j] : 0.f;
            float cb = pd ? cB[j] : 0.f;
            ev += ca * e[j];
            mk += cb * e[j];
        }
        #pragma unroll
        for (int j = 0; j < NC; ++j) if (j == t) e[j] = ev;

        float sem = ev * mk, see = ev * ev;
        for (int o = 32; o; o >>= 1) { sem += __shfl_down(sem, o); see += __shfl_down(see, o); }
        if (lane == 0) { red[w][0] = sem; red[w][1] = see; }
        __syncthreads();
        sem = 0.f; see = 0.f;
        #pragma unroll
        for (int u = 0; u < 8; ++u) { sem += red[u][0]; see += red[u][1]; }

        float At = Aarr[b * NC + t], Bt = Barr[b * NC + t], kkt = kkarr[b * NC + t];
        float p2 = pi * pi;
        float fro2 = At * At * n2 + 2.f * At * Bt * p2 * sem + Bt * Bt * p2 * see * kkt;
        float fro = sqrtf(fro2);
        float scale = fminf(30.f / (fro + 1e-6f), 1.f);
        if (tid == 0) pi_arr[b * 65 + t] = pi;
        n2 = scale * scale * fro2;
        pi *= scale * At;

        Eg[((long)(b * NC + t)) * DIM + tid] = ev;
        Eth[(long)b * DIM * NC + (long)tid * NC + t] = (bf16_t)ev;
    }
    if (tid == 0) pi_arr[b * 65 + NC] = pi;
}

// ---------------------------------------------------------------------------
// Generic bf16 MFMA GEMM: C[r][o] = sum_k A[r][k] * B[o][k]  (i.e. A @ B^T)
// 128xBN tile, BK=64, 256 threads (4 waves), 16x16x32 bf16 MFMA, fp32 accum.
// Optional second K-segment (K6: + Sh @ Eth^T) and per-batch B.
// ---------------------------------------------------------------------------
#define LDSP 72   // padded LDS row stride (elements) -> conflict-free b128 reads

template<int BN, int MODE, bool SEG2, bool BATCH_B>
__global__ __launch_bounds__(256) void gemm_k(
    const bf16_t* __restrict__ A, int lda,
    const bf16_t* __restrict__ Bm, int ldb, long bstride,
    int K1,
    const bf16_t* __restrict__ A2, const bf16_t* __restrict__ B2, long b2stride,
    float* __restrict__ Cf, bf16_t* __restrict__ Ch, int ldc,
    const bf16_t* __restrict__ resid,
    const float* __restrict__ pi_arr, const float* __restrict__ phi)
{
    constexpr int BM = 128;
    constexpr int WN = BN / 2;
    constexpr int FN = WN / 16;
    __shared__ bf16_t sA[BM * LDSP];
    __shared__ bf16_t sB[BN * LDSP];

    const int tid = threadIdx.x;
    const int lane = tid & 63;
    const int wid = tid >> 6;
    const int row0 = blockIdx.x * BM;
    const int col0 = blockIdx.y * BN;
    const int batch = row0 >> 12;   // 4096 rows per batch (valid for ROWS-sized GEMMs)
    const bf16_t* Bp = Bm + (BATCH_B ? (long)batch * bstride : 0);

    const int wm = wid >> 1, wn = wid & 1;
    const int n16 = lane & 15, q = lane >> 4;

    f32x4 acc[4][FN];
    #pragma unroll
    for (int fm = 0; fm < 4; ++fm)
        #pragma unroll
        for (int fn = 0; fn < FN; ++fn)
            acc[fm][fn] = (f32x4){0.f, 0.f, 0.f, 0.f};

    const int nk1 = K1 >> 6;
    const int nk = nk1 + (SEG2 ? 1 : 0);
    for (int kb = 0; kb < nk; ++kb) {
        __syncthreads();
        const bool s2 = SEG2 && (kb == nk1);
        {
            const bf16_t* src; long ld; int kbase;
            if (s2) { src = A2; ld = 64; kbase = 0; }
            else    { src = A;  ld = lda; kbase = kb * 64; }
            #pragma unroll
            for (int ii = 0; ii < BM / 32; ++ii) {
                int c = ii * 256 + tid;
                int r = c >> 3, p = c & 7;
                bf16x8 v = *(const bf16x8*)(src + (long)(row0 + r) * ld + kbase + p * 8);
                *(bf16x8*)&sA[r * LDSP + p * 8] = v;
            }
            const bf16_t* bsrc; long bld; int bkbase;
            if (s2) { bsrc = B2 + (long)batch * b2stride; bld = 64; bkbase = 0; }
            else    { bsrc = Bp; bld = ldb; bkbase = kb * 64; }
            #pragma unroll
            for (int ii = 0; ii < BN / 32; ++ii) {
                int c = ii * 256 + tid;
                int r = c >> 3, p = c & 7;
                bf16x8 v = *(const bf16x8*)(bsrc + (long)(col0 + r) * bld + bkbase + p * 8);
                *(bf16x8*)&sB[r * LDSP + p * 8] = v;
            }
        }
        __syncthreads();
        #pragma unroll
        for (int ks = 0; ks < 64; ks += 32) {
            bf16x8 af[4], bfr[FN];
            #pragma unroll
            for (int fm = 0; fm < 4; ++fm)
                af[fm] = *(const bf16x8*)&sA[(wm * 64 + fm * 16 + n16) * LDSP + ks + q * 8];
            #pragma unroll
            for (int fn = 0; fn < FN; ++fn)
                bfr[fn] = *(const bf16x8*)&sB[(wn * WN + fn * 16 + n16) * LDSP + ks + q * 8];
            #pragma unroll
            for (int fm = 0; fm < 4; ++fm)
                #pragma unroll
                for (int fn = 0; fn < FN; ++fn)
                    acc[fm][fn] = __builtin_amdgcn_mfma_f32_16x16x32_bf16(af[fm], bfr[fn], acc[fm][fn], 0, 0, 0);
        }
    }

    // epilogue: D row = q*4 + rg, col = n16 within each 16x16 frag
    #pragma unroll
    for (int fm = 0; fm < 4; ++fm) {
        #pragma unroll
        for (int fn = 0; fn < FN; ++fn) {
            #pragma unroll
            for (int rg = 0; rg < 4; ++rg) {
                int row = row0 + wm * 64 + fm * 16 + q * 4 + rg;
                int col = col0 + wn * WN + fn * 16 + n16;
                float v = acc[fm][fn][rg];
                if constexpr (MODE == MODE_F32) {
                    Cf[(long)row * ldc + col] = v;
                } else if constexpr (MODE == MODE_BF16) {
                    Ch[(long)row * ldc + col] = (bf16_t)v;
                } else if constexpr (MODE == MODE_SILU) {
                    float s = v * sigmoidf_(v);
                    Ch[(long)row * ldc + col] = (bf16_t)s;
                } else if constexpr (MODE == MODE_RESID) {
                    Cf[(long)row * ldc + col] = v + (float)resid[(long)row * ldc + col];
                } else if constexpr (MODE == MODE_MASKPHI) {
                    int b = row >> 12, tc = (row >> 6) & 63;
                    float o = (col < tc) ? v * phi[b * NC + col] : 0.f;
                    Ch[(long)row * ldc + col] = (bf16_t)o;
                } else {  // MODE_PI
                    int b = row >> 12, tc = (row >> 6) & 63;
                    Ch[(long)row * ldc + col] = (bf16_t)(v * pi_arr[b * 65 + tc]);
                }
            }
        }
    }
}

// ---------------------------------------------------------------------------
// K9: M_final[b][o][i] = pi64 * ( M0[o][i] + sum_j phi_j e~_j[o] k_j[i] )
// ---------------------------------------------------------------------------
__global__ __launch_bounds__(256) void k9_mfinal(
    const float* __restrict__ M0, const float* __restrict__ kf, const float* __restrict__ Eg,
    const float* __restrict__ phiarr, const float* __restrict__ pi_arr,
    float* __restrict__ out_Mf)
{
    int b = blockIdx.y, o0 = blockIdx.x * 32;
    int tid = threadIdx.x;
    __shared__ float wsm[32][NC];
    for (int l = tid; l < 32 * NC; l += 256) {
        int oo = l >> 6, j = l & 63;
        wsm[oo][j] = phiarr[b * NC + j] * Eg[((long)(b * NC + j)) * DIM + (o0 + oo)];
    }
    __syncthreads();
    float pi64 = pi_arr[b * 65 + NC];
    for (int half = 0; half < 2; ++half) {
        int i = half * 256 + tid;
        float accv[32];
        #pragma unroll
        for (int oo = 0; oo < 32; ++oo) accv[oo] = 0.f;
        for (int j = 0; j < NC; ++j) {
            float kj = kf[((long)(b * NC + j)) * DIM + i];
            #pragma unroll
            for (int oo = 0; oo < 32; ++oo) accv[oo] += wsm[oo][j] * kj;
        }
        #pragma unroll
        for (int oo = 0; oo < 32; ++oo) {
            long o = (long)(o0 + oo) * DIM + i;
            out_Mf[(long)b * DIM * DIM + o] = pi64 * (M0[o] + accv[oo]);
        }
    }
}

// ---------------------------------------------------------------------------
// launcher
// ---------------------------------------------------------------------------
extern "C" void kernel_launch(void* const* d_in, const int* in_sizes, int n_in,
                              void* d_out, int out_size, void* d_ws, size_t ws_size,
                              hipStream_t stream) {
    const float* x         = (const float*)d_in[0];
    const float* M0        = (const float*)d_in[1];
    const float* eta_raw   = (const float*)d_in[2];
    const float* alpha_raw = (const float*)d_in[3];
    const float* gate_w    = (const float*)d_in[4];
    const float* gate_b    = (const float*)d_in[5];
    const float* W1        = (const float*)d_in[6];
    const float* W2        = (const float*)d_in[7];
    float* out = (float*)d_out;

    char* ws = (char*)d_ws;
    size_t off = 0;
    auto alloc = [&](size_t bytes) -> char* {
        char* p = ws + off;
        off += (bytes + 255) & ~(size_t)255;
        return p;
    };
    // ~153 MB total workspace
    bf16_t* xh    = (bf16_t*)alloc((size_t)ROWS * DIM * 2);   // 64 MB
    bf16_t* outh  = (bf16_t*)alloc((size_t)ROWS * DIM * 2);   // 64 MB
    bf16_t* Sh    = (bf16_t*)alloc((size_t)ROWS * NC * 2);    // 8 MB
    bf16_t* dvh   = (bf16_t*)alloc((size_t)1024 * DIM * 2);   // 1 MB  (must be..
    bf16_t* kh    = (bf16_t*)alloc((size_t)1024 * DIM * 2);   // 1 MB  ..contiguous with dvh)
    bf16_t* M0h   = (bf16_t*)alloc((size_t)DIM * DIM * 2);
    bf16_t* W1h   = (bf16_t*)alloc((size_t)DIM * DIM * 2);
    bf16_t* W2h   = (bf16_t*)alloc((size_t)DIM * DIM * 2);
    float*  err0  = (float*)alloc((size_t)2048 * DIM * 4);    // 4 MB
    float*  kf    = (float*)alloc((size_t)1024 * DIM * 4);    // 2 MB
    float*  dvf   = (float*)alloc((size_t)1024 * DIM * 4);    // 2 MB
    float*  KD    = (float*)alloc((size_t)NB * NC * NC * 4);  // 1 MB
    float*  KK    = (float*)alloc((size_t)NB * NC * NC * 4);  // 1 MB
    float*  Eg    = (float*)alloc((size_t)1024 * DIM * 4);    // 2 MB
    bf16_t* Eth   = (bf16_t*)alloc((size_t)NB * DIM * NC * 2);// 1 MB
    float*  Aarr  = (float*)alloc(1024 * 4);
    float*  Barr  = (float*)alloc(1024 * 4);
    float*  phiarr= (float*)alloc(1024 * 4);
    float*  kkarr = (float*)alloc(1024 * 4);
    float*  pi_arr= (float*)alloc(NB * 65 * 4);
    float*  n2slot= (float*)alloc(256);
    bf16_t* Hh = xh;  // alias: xh is dead after K6

    (void)in_sizes; (void)n_in; (void)out_size; (void)ws_size;

    hipMemsetAsync(n2slot, 0, 4, stream);

    // K0: weight conversions + ||M0||^2
    k0_convert<<<3072, 256, 0, stream>>>(M0, W1, W2, M0h, W1h, W2h, n2slot);

    // K1: chunk stats (+ x -> bf16)
    k1_stats<<<dim3(NC, NB), 256, 0, stream>>>(x, gate_w, gate_b, eta_raw, alpha_raw,
                                               xh, kf, kh, dvf, dvh,
                                               Aarr, Barr, phiarr, kkarr);

    // K2: err0/Mk0 = [dvec; k] @ M0^T   (2048 x 512 @ 512 x 512, fp32 out)
    gemm_k<128, MODE_F32, false, false><<<dim3(16, 4), 256, 0, stream>>>(
        dvh, DIM, M0h, DIM, 0, DIM, nullptr, nullptr, 0,
        err0, nullptr, DIM, nullptr, nullptr, nullptr);

    // K3: Gram matrices
    k3_gram<<<dim3(NC, NB), 256, 0, stream>>>(kf, dvf, KD, KK);

    // K4: sequential chain (the only sequential part)
    k4_chain<<<NB, 512, 0, stream>>>(err0, KD, KK, Aarr, Barr, phiarr, kkarr, n2slot,
                                     Eg, Eth, pi_arr);

    // K5: scores Sh = mask(j<tc) * phi_j * (x @ k_j)   (per-batch B)
    gemm_k<64, MODE_MASKPHI, false, true><<<dim3(ROWS / 128, 1), 256, 0, stream>>>(
        xh, DIM, kh, DIM, (long)NC * DIM, DIM, nullptr, nullptr, 0,
        nullptr, Sh, NC, nullptr, nullptr, phiarr);

    // K6: outputs = pi_tc * ( x @ M0^T + Sh @ Eth^T )   (K = 512 + 64 segments)
    gemm_k<128, MODE_PI, true, false><<<dim3(ROWS / 128, 4), 256, 0, stream>>>(
        xh, DIM, M0h, DIM, 0, DIM, Sh, Eth, (long)DIM * NC,
        nullptr, outh, DIM, nullptr, pi_arr, nullptr);

    // K7: H = silu(outputs @ W1^T)
    gemm_k<128, MODE_SILU, false, false><<<dim3(ROWS / 128, 4), 256, 0, stream>>>(
        outh, DIM, W1h, DIM, 0, DIM, nullptr, nullptr, 0,
        nullptr, Hh, DIM, nullptr, nullptr, nullptr);

    // K8: v_hat = H @ W2^T + outputs   (fp32 to d_out)
    gemm_k<128, MODE_RESID, false, false><<<dim3(ROWS / 128, 4), 256, 0, stream>>>(
        Hh, DIM, W2h, DIM, 0, DIM, nullptr, nullptr, 0,
        out, nullptr, DIM, outh, nullptr, nullptr);

    // K9: M_final
    k9_mfinal<<<dim3(16, NB), 256, 0, stream>>>(M0, kf, Eg, phiarr, pi_arr,
                                                out + VHAT_ELEMS);
}

// Round 2
// 726.625 us; speedup vs baseline: 1.1127x; 1.1127x over previous
//
#include <hip/hip_runtime.h>
#include <cstdint>

// ---------------------------------------------------------------------------
// HopeAttention restructured:
//   M_t = a_t M_{t-1} + b_t err_t k_t^T  (gate+clip folded into a,b)
//   err_t = M_{t-1} (cmean_t - kmean_t)  (v_mean = M cmean since out linear in chunk)
//   => M_t = pi_t ( M0 + sum_j phi_j e~_j k_j^T ),  phi_j = B_j/A_j
//      e~ solves (I - L) E = Err0 with L[t][j] = phi_j KD[t][j] (strict lower tri)
//      -> T = (I-L)^{-1} per batch (tiny, in LDS), then E = T @ Err0 (parallel)
//   out_t = pi_t ( chunk_t @ M0^T + sum_{j<t} phi_j (chunk_t . k_j) e~_j^T )
//   ||M||_F^2 tracked analytically -> scalar-only sequential chain.
// ---------------------------------------------------------------------------

typedef __bf16 bf16_t;
typedef __bf16 bf16x8 __attribute__((ext_vector_type(8)));
typedef float f32x4 __attribute__((ext_vector_type(4)));

#define NB 16
#define SEQ 4096
#define DIM 512
#define CHK 64
#define NC 64
#define ROWS (NB * SEQ)   // 65536
#define VHAT_ELEMS ((long)ROWS * DIM)  // 33554432

enum { MODE_F32 = 0, MODE_BF16 = 1, MODE_SILU = 2, MODE_RESID = 3, MODE_MASKPHI = 4, MODE_PI = 5 };

static __device__ __forceinline__ float sigmoidf_(float z) { return 1.f / (1.f + __expf(-z)); }

// ---------------------------------------------------------------------------
// K0: convert weights to bf16 + ||M0||^2 reduction
// ---------------------------------------------------------------------------
__global__ __launch_bounds__(256) void k0_convert(
    const float* __restrict__ M0, const float* __restrict__ W1, const float* __restrict__ W2,
    bf16_t* __restrict__ M0h, bf16_t* __restrict__ W1h, bf16_t* __restrict__ W2h,
    float* __restrict__ n2slot)
{
    int idx = blockIdx.x * 256 + threadIdx.x;
    const int NW = DIM * DIM;
    if (idx < NW) {
        float v = M0[idx];
        M0h[idx] = (bf16_t)v;
        float s = v * v;
        for (int o = 32; o; o >>= 1) s += __shfl_down(s, o);
        if ((threadIdx.x & 63) == 0) atomicAdd(n2slot, s);
    } else if (idx < 2 * NW) {
        int i = idx - NW;
        W1h[i] = (bf16_t)W1[i];
    } else {
        int i = idx - 2 * NW;
        W2h[i] = (bf16_t)W2[i];
    }
}

// ---------------------------------------------------------------------------
// K1: per (b,tc): row norms, k_mean, cmean, dvec, gate scalars; also x -> bf16
// ---------------------------------------------------------------------------
__global__ __launch_bounds__(256) void k1_stats(
    const float* __restrict__ x,
    const float* __restrict__ gate_w, const float* __restrict__ gate_b,
    const float* __restrict__ eta_raw, const float* __restrict__ alpha_raw,
    bf16_t* __restrict__ xh,
    float* __restrict__ kf, bf16_t* __restrict__ kh,
    float* __restrict__ dvf, bf16_t* __restrict__ dvh,
    float* __restrict__ Aarr, float* __restrict__ Barr,
    float* __restrict__ phiarr, float* __restrict__ kkarr)
{
    int tc = blockIdx.x, b = blockIdx.y;
    int tid = threadIdx.x, lane = tid & 63, w = tid >> 6;
    __shared__ float invn[CHK];
    __shared__ float redg[4], redk[4];
    long base = ((long)b * SEQ + (long)tc * CHK) * DIM;

    // pass 1: row norms (wave per 16 rows) + bf16 copy of x
    for (int c = w * 16; c < w * 16 + 16; ++c) {
        const float* row = x + base + (long)c * DIM;
        float4 v0 = ((const float4*)row)[lane * 2];
        float4 v1 = ((const float4*)row)[lane * 2 + 1];
        bf16x8 hv;
        hv[0] = (bf16_t)v0.x; hv[1] = (bf16_t)v0.y; hv[2] = (bf16_t)v0.z; hv[3] = (bf16_t)v0.w;
        hv[4] = (bf16_t)v1.x; hv[5] = (bf16_t)v1.y; hv[6] = (bf16_t)v1.z; hv[7] = (bf16_t)v1.w;
        *(bf16x8*)(xh + base + (long)c * DIM + lane * 8) = hv;
        float s = v0.x*v0.x + v0.y*v0.y + v0.z*v0.z + v0.w*v0.w
                + v1.x*v1.x + v1.y*v1.y + v1.z*v1.z + v1.w*v1.w;
        for (int o = 32; o; o >>= 1) s += __shfl_down(s, o);
        if (lane == 0) {
            float nm = sqrtf(s);
            invn[c] = 1.f / fmaxf(nm, 1e-5f);
        }
    }
    __syncthreads();

    // pass 2: k_mean / cmean over dims
    float pg = 0.f, pkk = 0.f;
    for (int half = 0; half < 2; ++half) {
        int i = half * 256 + tid;
        float s0 = 0.f, s1 = 0.f;
        for (int c = 0; c < CHK; ++c) {
            float v = x[base + (long)c * DIM + i];
            s0 += v;
            s1 += v * invn[c];
        }
        float kv = s1 * (1.f / 64.f);
        float cm = s0 * (1.f / 64.f);
        float dv = cm - kv;
        long o = ((long)b * NC + tc) * DIM + i;
        kf[o] = kv; kh[o] = (bf16_t)kv;
        dvf[o] = dv; dvh[o] = (bf16_t)dv;
        pg += kv * gate_w[i];
        pkk += kv * kv;
    }
    for (int o = 32; o; o >>= 1) { pg += __shfl_down(pg, o); pkk += __shfl_down(pkk, o); }
    if (lane == 0) { redg[w] = pg; redk[w] = pkk; }
    __syncthreads();
    if (tid == 0) {
        float gdot = redg[0] + redg[1] + redg[2] + redg[3] + gate_b[0];
        float kk = redk[0] + redk[1] + redk[2] + redk[3];
        float g = sigmoidf_(gdot);
        float eta = 0.2f * sigmoidf_(eta_raw[0]);
        float alpha = 0.5f + 0.5f * sigmoidf_(alpha_raw[0]);
        float Av = g * alpha + 1.f - g;
        float Bv = g * eta;
        int idx = b * NC + tc;
        Aarr[idx] = Av; Barr[idx] = Bv; phiarr[idx] = Bv / Av; kkarr[idx] = kk;
    }
}

// ---------------------------------------------------------------------------
// K3: Gram matrices KD[b][t][j] = k_j . dvec_t,  KK[b][t][j] = k_j . k_t
// ---------------------------------------------------------------------------
__global__ __launch_bounds__(256) void k3_gram(
    const float* __restrict__ kf, const float* __restrict__ dvf,
    float* __restrict__ KD, float* __restrict__ KK)
{
    int t = blockIdx.x, b = blockIdx.y;
    int tid = threadIdx.x, lane = tid & 63, w = tid >> 6;
    __shared__ float dvt[DIM], ktv[DIM];
    for (int i = tid; i < DIM; i += 256) {
        long o = ((long)b * NC + t) * DIM + i;
        dvt[i] = dvf[o];
        ktv[i] = kf[o];
    }
    __syncthreads();
    for (int j = w * 16; j < w * 16 + 16; ++j) {
        const float* kj = kf + ((long)b * NC + j) * DIM;
        float s1 = 0.f, s2 = 0.f;
        #pragma unroll
        for (int u = 0; u < 8; ++u) {
            float v = kj[lane * 8 + u];
            s1 += v * dvt[lane * 8 + u];
            s2 += v * ktv[lane * 8 + u];
        }
        for (int o = 32; o; o >>= 1) { s1 += __shfl_down(s1, o); s2 += __shfl_down(s2, o); }
        if (lane == 0) {
            KD[((long)b * NC + t) * NC + j] = s1;
            KK[((long)b * NC + t) * NC + j] = s2;
        }
    }
}

// ---------------------------------------------------------------------------
// K4a: per-batch T = (I - L)^{-1}, L[t][j] = phi_j*KD[t][j] (strict lower tri).
// 64 threads; lane i owns COLUMN i of T (in LDS) -> forward substitution has
// no cross-lane dependency and needs no barriers inside the t-loop.
// ---------------------------------------------------------------------------
__global__ __launch_bounds__(64) void k4a_T(
    const float* __restrict__ KD, const float* __restrict__ phiarr,
    float* __restrict__ Tg)
{
    int b = blockIdx.x;
    int i = threadIdx.x;  // 0..63, owns column i
    __shared__ float Ls[NC * NC];
    __shared__ float Ts[NC * 65];
    float phii = phiarr[b * NC + i];
    for (int t = 0; t < NC; ++t)
        Ls[t * NC + i] = (i < t) ? phii * KD[((long)b * NC + t) * NC + i] : 0.f;
    __syncthreads();
    for (int t = 0; t < NC; ++t) {
        float s = (i == t) ? 1.f : 0.f;
        for (int j = 0; j < t; ++j)
            s += Ls[t * NC + j] * Ts[j * 65 + i];   // Ls: broadcast; Ts: own column
        Ts[t * 65 + i] = s;
    }
    for (int t = 0; t < NC; ++t)
        Tg[((long)b * NC + t) * NC + i] = Ts[t * 65 + i];
}

// ---------------------------------------------------------------------------
// K4b_E: E_t = T[t] @ Err0dv  (per (b,t) block). Writes Eg (fp32) + Eth (bf16^T).
// ---------------------------------------------------------------------------
__global__ __launch_bounds__(256) void k4b_E(
    const float* __restrict__ Tg, const float* __restrict__ err0,
    float* __restrict__ Eg, bf16_t* __restrict__ Eth)
{
    int t = blockIdx.x, b = blockIdx.y;
    int tid = threadIdx.x;
    __shared__ float sT[NC];
    if (tid < NC) sT[tid] = Tg[((long)b * NC + t) * NC + tid];
    __syncthreads();
    #pragma unroll
    for (int half = 0; half < 2; ++half) {
        int d = half * 256 + tid;
        float s = 0.f;
        #pragma unroll 4
        for (int j = 0; j < NC; ++j)
            s += sT[j] * err0[((long)(b * NC + j)) * DIM + d];
        Eg[((long)(b * NC + t)) * DIM + d] = s;
        Eth[(long)b * DIM * NC + (long)d * NC + t] = (bf16_t)s;
    }
}

// ---------------------------------------------------------------------------
// K4b_M: MK_t = Mk0_t + sum_{j<t} phi_j KK[t][j] E_j ; reduce sem = E_t.MK_t,
// see = E_t.E_t.
// ---------------------------------------------------------------------------
__global__ __launch_bounds__(256) void k4b_M(
    const float* __restrict__ KK, const float* __restrict__ phiarr,
    const float* __restrict__ err0, const float* __restrict__ Eg,
    float* __restrict__ semarr, float* __restrict__ seearr)
{
    int t = blockIdx.x, b = blockIdx.y;
    int tid = threadIdx.x, lane = tid & 63, w = tid >> 6;
    __shared__ float sL[NC];
    __shared__ float red[4][2];
    if (tid < NC) {
        float ph = phiarr[b * NC + tid];
        sL[tid] = (tid < t) ? ph * KK[((long)b * NC + t) * NC + tid] : 0.f;
    }
    __syncthreads();
    float sem = 0.f, see = 0.f;
    #pragma unroll
    for (int half = 0; half < 2; ++half) {
        int d = half * 256 + tid;
        float m = err0[((long)(1024 + b * NC + t)) * DIM + d];
        for (int j = 0; j < t; ++j)
            m += sL[j] * Eg[((long)(b * NC + j)) * DIM + d];
        float e = Eg[((long)(b * NC + t)) * DIM + d];
        sem += e * m;
        see += e * e;
    }
    for (int o = 32; o; o >>= 1) { sem += __shfl_down(sem, o); see += __shfl_down(see, o); }
    if (lane == 0) { red[w][0] = sem; red[w][1] = see; }
    __syncthreads();
    if (tid == 0) {
        semarr[b * NC + t] = red[0][0] + red[1][0] + red[2][0] + red[3][0];
        seearr[b * NC + t] = red[0][1] + red[1][1] + red[2][1] + red[3][1];
    }
}

// ---------------------------------------------------------------------------
// K4c: scalar pi/n2 chain. 1 block, lane b handles batch b. Pure scalars.
// ---------------------------------------------------------------------------
__global__ __launch_bounds__(64) void k4c_chain(
    const float* __restrict__ Aarr, const float* __restrict__ Barr,
    const float* __restrict__ kkarr, const float* __restrict__ n2slot,
    const float* __restrict__ semarr, const float* __restrict__ seearr,
    float* __restrict__ pi_arr)
{
    int b = threadIdx.x;
    if (b >= NB) return;
    float n2 = n2slot[0];
    float pi = 1.f;
    for (int t = 0; t < NC; ++t) {
        int idx = b * NC + t;
        float At = Aarr[idx], Bt = Barr[idx], kkt = kkarr[idx];
        float sem = semarr[idx], see = seearr[idx];
        float p2 = pi * pi;
        float fro2 = At * At * n2 + 2.f * At * Bt * p2 * sem + Bt * Bt * p2 * see * kkt;
        float fro = sqrtf(fro2);
        float scale = fminf(30.f / (fro + 1e-6f), 1.f);
        pi_arr[b * 65 + t] = pi;
        n2 = scale * scale * fro2;
        pi *= scale * At;
    }
    pi_arr[b * 65 + NC] = pi;
}

// ---------------------------------------------------------------------------
// Generic bf16 MFMA GEMM: C[r][o] = sum_k A[r][k] * B[o][k]  (i.e. A @ B^T)
// 128xBN tile, BK=64, 256 threads (4 waves), 16x16x32 bf16 MFMA, fp32 accum.
// Optional second K-segment (K6: + Sh @ Eth^T) and per-batch B.
// ---------------------------------------------------------------------------
#define LDSP 72   // padded LDS row stride (elements) -> conflict-free b128 reads

template<int BN, int MODE, bool SEG2, bool BATCH_B>
__global__ __launch_bounds__(256) void gemm_k(
    const bf16_t* __restrict__ A, int lda,
    const bf16_t* __restrict__ Bm, int ldb, long bstride,
    int K1,
    const bf16_t* __restrict__ A2, const bf16_t* __restrict__ B2, long b2stride,
    float* __restrict__ Cf, bf16_t* __restrict__ Ch, int ldc,
    const bf16_t* __restrict__ resid,
    const float* __restrict__ pi_arr, const float* __restrict__ phi)
{
    constexpr int BM = 128;
    constexpr int WN = BN / 2;
    constexpr int FN = WN / 16;
    __shared__ bf16_t sA[BM * LDSP];
    __shared__ bf16_t sB[BN * LDSP];

    const int tid = threadIdx.x;
    const int lane = tid & 63;
    const int wid = tid >> 6;
    const int row0 = blockIdx.x * BM;
    const int col0 = blockIdx.y * BN;
    const int batch = row0 >> 12;   // 4096 rows per batch (valid for ROWS-sized GEMMs)
    const bf16_t* Bp = Bm + (BATCH_B ? (long)batch * bstride : 0);

    const int wm = wid >> 1, wn = wid & 1;
    const int n16 = lane & 15, q = lane >> 4;

    f32x4 acc[4][FN];
    #pragma unroll
    for (int fm = 0; fm < 4; ++fm)
        #pragma unroll
        for (int fn = 0; fn < FN; ++fn)
            acc[fm][fn] = (f32x4){0.f, 0.f, 0.f, 0.f};

    const int nk1 = K1 >> 6;
    const int nk = nk1 + (SEG2 ? 1 : 0);
    for (int kb = 0; kb < nk; ++kb) {
        __syncthreads();
        const bool s2 = SEG2 && (kb == nk1);
        {
            const bf16_t* src; long ld; int kbase;
            if (s2) { src = A2; ld = 64; kbase = 0; }
            else    { src = A;  ld = lda; kbase = kb * 64; }
            #pragma unroll
            for (int ii = 0; ii < BM / 32; ++ii) {
                int c = ii * 256 + tid;
                int r = c >> 3, p = c & 7;
                bf16x8 v = *(const bf16x8*)(src + (long)(row0 + r) * ld + kbase + p * 8);
                *(bf16x8*)&sA[r * LDSP + p * 8] = v;
            }
            const bf16_t* bsrc; long bld; int bkbase;
            if (s2) { bsrc = B2 + (long)batch * b2stride; bld = 64; bkbase = 0; }
            else    { bsrc = Bp; bld = ldb; bkbase = kb * 64; }
            #pragma unroll
            for (int ii = 0; ii < BN / 32; ++ii) {
                int c = ii * 256 + tid;
                int r = c >> 3, p = c & 7;
                bf16x8 v = *(const bf16x8*)(bsrc + (long)(col0 + r) * bld + bkbase + p * 8);
                *(bf16x8*)&sB[r * LDSP + p * 8] = v;
            }
        }
        __syncthreads();
        #pragma unroll
        for (int ks = 0; ks < 64; ks += 32) {
            bf16x8 af[4], bfr[FN];
            #pragma unroll
            for (int fm = 0; fm < 4; ++fm)
                af[fm] = *(const bf16x8*)&sA[(wm * 64 + fm * 16 + n16) * LDSP + ks + q * 8];
            #pragma unroll
            for (int fn = 0; fn < FN; ++fn)
                bfr[fn] = *(const bf16x8*)&sB[(wn * WN + fn * 16 + n16) * LDSP + ks + q * 8];
            #pragma unroll
            for (int fm = 0; fm < 4; ++fm)
                #pragma unroll
                for (int fn = 0; fn < FN; ++fn)
                    acc[fm][fn] = __builtin_amdgcn_mfma_f32_16x16x32_bf16(af[fm], bfr[fn], acc[fm][fn], 0, 0, 0);
        }
    }

    // epilogue: D row = q*4 + rg, col = n16 within each 16x16 frag
    #pragma unroll
    for (int fm = 0; fm < 4; ++fm) {
        #pragma unroll
        for (int fn = 0; fn < FN; ++fn) {
            #pragma unroll
            for (int rg = 0; rg < 4; ++rg) {
                int row = row0 + wm * 64 + fm * 16 + q * 4 + rg;
                int col = col0 + wn * WN + fn * 16 + n16;
                float v = acc[fm][fn][rg];
                if constexpr (MODE == MODE_F32) {
                    Cf[(long)row * ldc + col] = v;
                } else if constexpr (MODE == MODE_BF16) {
                    Ch[(long)row * ldc + col] = (bf16_t)v;
                } else if constexpr (MODE == MODE_SILU) {
                    float s = v * sigmoidf_(v);
                    Ch[(long)row * ldc + col] = (bf16_t)s;
                } else if constexpr (MODE == MODE_RESID) {
                    Cf[(long)row * ldc + col] = v + (float)resid[(long)row * ldc + col];
                } else if constexpr (MODE == MODE_MASKPHI) {
                    int b = row >> 12, tc = (row >> 6) & 63;
                    float o = (col < tc) ? v * phi[b * NC + col] : 0.f;
                    Ch[(long)row * ldc + col] = (bf16_t)o;
                } else {  // MODE_PI
                    int b = row >> 12, tc = (row >> 6) & 63;
                    Ch[(long)row * ldc + col] = (bf16_t)(v * pi_arr[b * 65 + tc]);
                }
            }
        }
    }
}

// ---------------------------------------------------------------------------
// K9: M_final[b][o][i] = pi64 * ( M0[o][i] + sum_j phi_j e~_j[o] k_j[i] )
// ---------------------------------------------------------------------------
__global__ __launch_bounds__(256) void k9_mfinal(
    const float* __restrict__ M0, const float* __restrict__ kf, const float* __restrict__ Eg,
    const float* __restrict__ phiarr, const float* __restrict__ pi_arr,
    float* __restrict__ out_Mf)
{
    int b = blockIdx.y, o0 = blockIdx.x * 32;
    int tid = threadIdx.x;
    __shared__ float wsm[32][NC];
    for (int l = tid; l < 32 * NC; l += 256) {
        int oo = l >> 6, j = l & 63;
        wsm[oo][j] = phiarr[b * NC + j] * Eg[((long)(b * NC + j)) * DIM + (o0 + oo)];
    }
    __syncthreads();
    float pi64 = pi_arr[b * 65 + NC];
    for (int half = 0; half < 2; ++half) {
        int i = half * 256 + tid;
        float accv[32];
        #pragma unroll
        for (int oo = 0; oo < 32; ++oo) accv[oo] = 0.f;
        for (int j = 0; j < NC; ++j) {
            float kj = kf[((long)(b * NC + j)) * DIM + i];
            #pragma unroll
            for (int oo = 0; oo < 32; ++oo) accv[oo] += wsm[oo][j] * kj;
        }
        #pragma unroll
        for (int oo = 0; oo < 32; ++oo) {
            long o = (long)(o0 + oo) * DIM + i;
            out_Mf[(long)b * DIM * DIM + o] = pi64 * (M0[o] + accv[oo]);
        }
    }
}

// ---------------------------------------------------------------------------
// launcher
// ---------------------------------------------------------------------------
extern "C" void kernel_launch(void* const* d_in, const int* in_sizes, int n_in,
                              void* d_out, int out_size, void* d_ws, size_t ws_size,
                              hipStream_t stream) {
    const float* x         = (const float*)d_in[0];
    const float* M0        = (const float*)d_in[1];
    const float* eta_raw   = (const float*)d_in[2];
    const float* alpha_raw = (const float*)d_in[3];
    const float* gate_w    = (const float*)d_in[4];
    const float* gate_b    = (const float*)d_in[5];
    const float* W1        = (const float*)d_in[6];
    const float* W2        = (const float*)d_in[7];
    float* out = (float*)d_out;

    char* ws = (char*)d_ws;
    size_t off = 0;
    auto alloc = [&](size_t bytes) -> char* {
        char* p = ws + off;
        off += (bytes + 255) & ~(size_t)255;
        return p;
    };
    bf16_t* xh    = (bf16_t*)alloc((size_t)ROWS * DIM * 2);   // 64 MB
    bf16_t* outh  = (bf16_t*)alloc((size_t)ROWS * DIM * 2);   // 64 MB
    bf16_t* Sh    = (bf16_t*)alloc((size_t)ROWS * NC * 2);    // 8 MB
    bf16_t* dvh   = (bf16_t*)alloc((size_t)1024 * DIM * 2);   // 1 MB  (must be..
    bf16_t* kh    = (bf16_t*)alloc((size_t)1024 * DIM * 2);   // 1 MB  ..contiguous with dvh)
    bf16_t* M0h   = (bf16_t*)alloc((size_t)DIM * DIM * 2);
    bf16_t* W1h   = (bf16_t*)alloc((size_t)DIM * DIM * 2);
    bf16_t* W2h   = (bf16_t*)alloc((size_t)DIM * DIM * 2);
    float*  err0  = (float*)alloc((size_t)2048 * DIM * 4);    // 4 MB
    float*  kf    = (float*)alloc((size_t)1024 * DIM * 4);    // 2 MB
    float*  dvf   = (float*)alloc((size_t)1024 * DIM * 4);    // 2 MB
    float*  KD    = (float*)alloc((size_t)NB * NC * NC * 4);  // 1 MB
    float*  KK    = (float*)alloc((size_t)NB * NC * NC * 4);  // 1 MB
    float*  Eg    = (float*)alloc((size_t)1024 * DIM * 4);    // 2 MB
    bf16_t* Eth   = (bf16_t*)alloc((size_t)NB * DIM * NC * 2);// 1 MB
    float*  Tg    = (float*)alloc((size_t)NB * NC * NC * 4);  // 256 KB
    float*  Aarr  = (float*)alloc(1024 * 4);
    float*  Barr  = (float*)alloc(1024 * 4);
    float*  phiarr= (float*)alloc(1024 * 4);
    float*  kkarr = (float*)alloc(1024 * 4);
    float*  semarr= (float*)alloc(1024 * 4);
    float*  seearr= (float*)alloc(1024 * 4);
    float*  pi_arr= (float*)alloc(NB * 65 * 4);
    float*  n2slot= (float*)alloc(256);
    bf16_t* Hh = xh;  // alias: xh is dead after K6

    (void)in_sizes; (void)n_in; (void)out_size; (void)ws_size;

    hipMemsetAsync(n2slot, 0, 4, stream);

    // K0: weight conversions + ||M0||^2
    k0_convert<<<3072, 256, 0, stream>>>(M0, W1, W2, M0h, W1h, W2h, n2slot);

    // K1: chunk stats (+ x -> bf16)
    k1_stats<<<dim3(NC, NB), 256, 0, stream>>>(x, gate_w, gate_b, eta_raw, alpha_raw,
                                               xh, kf, kh, dvf, dvh,
                                               Aarr, Barr, phiarr, kkarr);

    // K2: err0/Mk0 = [dvec; k] @ M0^T   (2048 x 512 @ 512 x 512, fp32 out)
    gemm_k<128, MODE_F32, false, false><<<dim3(16, 4), 256, 0, stream>>>(
        dvh, DIM, M0h, DIM, 0, DIM, nullptr, nullptr, 0,
        err0, nullptr, DIM, nullptr, nullptr, nullptr);

    // K3: Gram matrices
    k3_gram<<<dim3(NC, NB), 256, 0, stream>>>(kf, dvf, KD, KK);

    // K4: triangular solve via explicit T = (I-L)^{-1} (parallel), then scalar chain
    k4a_T<<<NB, 64, 0, stream>>>(KD, phiarr, Tg);
    k4b_E<<<dim3(NC, NB), 256, 0, stream>>>(Tg, err0, Eg, Eth);
    k4b_M<<<dim3(NC, NB), 256, 0, stream>>>(KK, phiarr, err0, Eg, semarr, seearr);
    k4c_chain<<<1, 64, 0, stream>>>(Aarr, Barr, kkarr, n2slot, semarr, seearr, pi_arr);

    // K5: scores Sh = mask(j<tc) * phi_j * (x @ k_j)   (per-batch B)
    gemm_k<64, MODE_MASKPHI, false, true><<<dim3(ROWS / 128, 1), 256, 0, stream>>>(
        xh, DIM, kh, DIM, (long)NC * DIM, DIM, nullptr, nullptr, 0,
        nullptr, Sh, NC, nullptr, nullptr, phiarr);

    // K6: outputs = pi_tc * ( x @ M0^T + Sh @ Eth^T )   (K = 512 + 64 segments)
    gemm_k<128, MODE_PI, true, false><<<dim3(ROWS / 128, 4), 256, 0, stream>>>(
        xh, DIM, M0h, DIM, 0, DIM, Sh, Eth, (long)DIM * NC,
        nullptr, outh, DIM, nullptr, pi_arr, nullptr);

    // K7: H = silu(outputs @ W1^T)
    gemm_k<128, MODE_SILU, false, false><<<dim3(ROWS / 128, 4), 256, 0, stream>>>(
        outh, DIM, W1h, DIM, 0, DIM, nullptr, nullptr, 0,
        nullptr, Hh, DIM, nullptr, nullptr, nullptr);

    // K8: v_hat = H @ W2^T + outputs   (fp32 to d_out)
    gemm_k<128, MODE_RESID, false, false><<<dim3(ROWS / 128, 4), 256, 0, stream>>>(
        Hh, DIM, W2h, DIM, 0, DIM, nullptr, nullptr, 0,
        out, nullptr, DIM, outh, nullptr, nullptr);

    // K9: M_final
    k9_mfinal<<<dim3(16, NB), 256, 0, stream>>>(M0, kf, Eg, phiarr, pi_arr,
                                                out + VHAT_ELEMS);
}